// Round 7
// baseline (486.838 us; speedup 1.0000x reference)
//
#include <hip/hip_runtime.h>

#define T_STEPS 512
#define HSTR 80        // f16 per h batch-row: 160B stride -> conflict-free b128 A-reads
#define XSTR 512       // f16 per x batch-row (reads are quad-uniform broadcasts)
#define NB 4           // batches per wave/block

typedef _Float16 half8v __attribute__((ext_vector_type(8)));
typedef _Float16 half4v __attribute__((ext_vector_type(4)));
typedef float f32x4 __attribute__((ext_vector_type(4)));

#define K1 1.442695041f    // log2(e)
#define K2 2.885390082f    // 2*log2(e)

__device__ __forceinline__ float ex2(float x) {
#if __has_builtin(__builtin_amdgcn_exp2f)
    return __builtin_amdgcn_exp2f(x);
#else
    return exp2f(x);
#endif
}
__device__ __forceinline__ float rcp_fast(float x) {
#if __has_builtin(__builtin_amdgcn_rcpf)
    return __builtin_amdgcn_rcpf(x);
#else
    return 1.0f / x;
#endif
}

// select vec[q] (q = lane>>4, uniform per quad); compiler hoists the 3 compares
#define SELQ(vec) (q == 0 ? (vec)[0] : q == 1 ? (vec)[1] : q == 2 ? (vec)[2] : (vec)[3])

// ONE wave (64 thr) per block, NB=4 batches, fully autonomous: no __syncthreads
// anywhere. Batch lives in MFMA M-rows with 4x replication (row % 4 = batch), so
// D reg-index = batch. The wave holds ALL weights (16 N-tiles, class-interleaved:
// tile 4*cls+j covers gate rows cls*64+16j+c) as f16 B-frags. h bounces through a
// wave-private 640B LDS tile ordered by lgkmcnt only (intra-wave, in-order).
__global__ __launch_bounds__(64, 1) void lstm_kernel(
    const float* __restrict__ x, const float* __restrict__ w_ih,
    const float* __restrict__ w_hh, const float* __restrict__ b_ih,
    const float* __restrict__ b_hh, const float* __restrict__ w_fc,
    const float* __restrict__ b_fc, float* __restrict__ out)
{
    __shared__ __align__(16) _Float16 hls[NB * HSTR];   // 640 B, h[batch][unit]
    __shared__ __align__(16) _Float16 xls[NB * XSTR];   // 4 KB,  x[batch][t]

    const int lane = threadIdx.x & 63;
    const int q    = lane >> 4;        // quad: batch this lane activates
    const int c    = lane & 15;        // unit-in-group / A-row index
    const int ab   = c & 3;            // A-row batch for this lane's A-frags
    const int b0   = blockIdx.x * NB;

    // ---- stage x -> LDS (f16); coalesced float4 reads, one wave ----
    for (int i = lane; i < NB * 128; i += 64) {     // 4 rows x 128 float4
        int b  = i >> 7;
        int t4 = i & 127;
        float4 v = *(const float4*)(x + (size_t)(b0 + b) * T_STEPS + t4 * 4);
        half4v hv;
        hv[0] = (_Float16)v.x; hv[1] = (_Float16)v.y;
        hv[2] = (_Float16)v.z; hv[3] = (_Float16)v.w;
        *(half4v*)(&xls[b * XSTR + t4 * 4]) = hv;
    }
    // zero h (h_{-1} = 0): 4*80 f16 = 160 dwords
    for (int i = lane; i < NB * HSTR / 2; i += 64) ((int*)hls)[i] = 0;

    // ---- full weight set as B-frags: tile 4*cls+j -> gate g = cls*64+16j+c ----
    // lane c+16q holds B[k=32kk+8q+jj][col c] = w_hh[g][32kk+8q+jj], f16
    half8v bw[16][2];
    float wihK[4][4], biasK[4][4], wfc[4];
    const float sK[4] = { -K1, -K1, K2, -K1 };      // arg prescale: i,f,o sig; g tanh
#pragma unroll
    for (int cls = 0; cls < 4; ++cls) {
#pragma unroll
        for (int j = 0; j < 4; ++j) {
            int g = cls * 64 + 16 * j + c;
            wihK[cls][j]  = w_ih[g] * sK[cls];
            biasK[cls][j] = (b_ih[g] + b_hh[g]) * sK[cls];
#pragma unroll
            for (int kk = 0; kk < 2; ++kk) {
                const float* wp = w_hh + g * 64 + 32 * kk + 8 * q;
                float4 lo = *(const float4*)(wp);
                float4 hi = *(const float4*)(wp + 4);
                half8v f;
                f[0] = (_Float16)lo.x; f[1] = (_Float16)lo.y;
                f[2] = (_Float16)lo.z; f[3] = (_Float16)lo.w;
                f[4] = (_Float16)hi.x; f[5] = (_Float16)hi.y;
                f[6] = (_Float16)hi.z; f[7] = (_Float16)hi.w;
                bw[4 * cls + j][kk] = f;
            }
        }
    }
#pragma unroll
    for (int j = 0; j < 4; ++j) wfc[j] = w_fc[16 * j + c];
    const float bfc = b_fc[0];

    float cs[4] = {0.f, 0.f, 0.f, 0.f};   // cell state: (batch q, unit 16j+c)

    float* outrow = out + (size_t)(b0 + q) * T_STEPS;

    for (int tq = 0; tq < 128; ++tq) {
        // x for this lane's batch q, 4 steps (quad-uniform broadcast read)
        half4v xh = *(const half4v*)(&xls[q * XSTR + tq * 4]);

#pragma unroll
        for (int dt = 0; dt < 4; ++dt) {
            const int t = tq * 4 + dt;
            const float xv = (float)xh[dt];

            // A-frags: A[m][k] = h[m&3][k]; lane row m=c, k=32kk+8q+jj
            const char* hb = (const char*)hls + ab * (HSTR * 2) + 16 * q;
            half8v a0 = *(const half8v*)(hb);        // kk=0
            half8v a1 = *(const half8v*)(hb + 64);   // kk=1

            // all 256 gates: 16 tiles x K=64
            f32x4 acc[16];
#pragma unroll
            for (int n = 0; n < 16; ++n) {
                f32x4 z = {0.f, 0.f, 0.f, 0.f};
                acc[n] = __builtin_amdgcn_mfma_f32_16x16x32_f16(a0, bw[n][0], z, 0, 0, 0);
                acc[n] = __builtin_amdgcn_mfma_f32_16x16x32_f16(a1, bw[n][1], acc[n], 0, 0, 0);
            }

            // this lane: batch q, units 16j+c. gate(cls,j) = acc[4cls+j][q]
            // v = sK*(gate + x*wih + bias)  (weights prescaled)
            float h4[4];
#pragma unroll
            for (int j = 0; j < 4; ++j) {
                float vI = fmaf(SELQ(acc[0*4+j]), -K1, fmaf(xv, wihK[0][j], biasK[0][j]));
                float vF = fmaf(SELQ(acc[1*4+j]), -K1, fmaf(xv, wihK[1][j], biasK[1][j]));
                float vG = fmaf(SELQ(acc[2*4+j]),  K2, fmaf(xv, wihK[2][j], biasK[2][j]));
                float vO = fmaf(SELQ(acc[3*4+j]), -K1, fmaf(xv, wihK[3][j], biasK[3][j]));
                float A  = ex2(vI);                       // e^{-i}
                float B  = ex2(vG);                       // e^{2g}
                float ig = (B - 1.0f) * rcp_fast((1.0f + A) * (1.0f + B));  // sig(i)*tanh(g)
                float rf = rcp_fast(1.0f + ex2(vF));      // sig(f)
                cs[j] = fmaf(cs[j], rf, ig);
                float cc = fminf(fmaxf(cs[j], -15.f), 15.f);
                float Ao = ex2(vO);                       // e^{-o}
                float C  = ex2(cc * K2);                  // e^{2c}
                float h  = (C - 1.0f) * rcp_fast((1.0f + Ao) * (1.0f + C)); // sig(o)*tanh(c)
                h4[j] = h;
                hls[q * HSTR + 16 * j + c] = (_Float16)h; // ds_write_b16
            }

            // fc: out[b0+q][t] = sum_u h[u][q]*wfc[u] + bfc (reduce over c-lanes)
            float s = h4[0] * wfc[0];
            s = fmaf(h4[1], wfc[1], s);
            s = fmaf(h4[2], wfc[2], s);
            s = fmaf(h4[3], wfc[3], s);
            s += __shfl_xor(s, 1);
            s += __shfl_xor(s, 2);
            s += __shfl_xor(s, 4);
            s += __shfl_xor(s, 8);
            if (c == 0) outrow[t] = s + bfc;   // async store, never waited on
        }
    }
}

extern "C" void kernel_launch(void* const* d_in, const int* in_sizes, int n_in,
                              void* d_out, int out_size, void* d_ws, size_t ws_size,
                              hipStream_t stream) {
    const float* x    = (const float*)d_in[0];
    const float* w_ih = (const float*)d_in[1];
    const float* w_hh = (const float*)d_in[2];
    const float* b_ih = (const float*)d_in[3];
    const float* b_hh = (const float*)d_in[4];
    const float* w_fc = (const float*)d_in[5];
    const float* b_fc = (const float*)d_in[6];
    float* out = (float*)d_out;
    hipLaunchKernelGGL(lstm_kernel, dim3(2048 / NB), dim3(64), 0, stream,
                       x, w_ih, w_hh, b_ih, b_hh, w_fc, b_fc, out);
}

// Round 9
// 272.894 us; speedup vs baseline: 1.7840x; 1.7840x over previous
//
#include <hip/hip_runtime.h>

#define T_STEPS 512
#define HSTR 72        // _Float16 per h batch-row (144 B; fits 64 units + pad)
#define XSTRIDE 520    // _Float16 per x-row
#define OSTRIDE 513    // floats per out-row
#define NB 8           // batches per block, 256 blocks = 1 block/CU

typedef _Float16 half8v __attribute__((ext_vector_type(8)));
typedef _Float16 half4v __attribute__((ext_vector_type(4)));
typedef float f32x4 __attribute__((ext_vector_type(4)));

#define K1 1.442695041f    // log2(e)
#define K2 2.885390082f    // 2*log2(e)

__device__ __forceinline__ float ex2(float x) {
#if __has_builtin(__builtin_amdgcn_exp2f)
    return __builtin_amdgcn_exp2f(x);
#else
    return exp2f(x);
#endif
}
__device__ __forceinline__ float rcp_fast(float x) {
#if __has_builtin(__builtin_amdgcn_rcpf)
    return __builtin_amdgcn_rcpf(x);
#else
    return 1.0f / x;
#endif
}

// partial fc-dot over this lane's A-frag slice (f16), reduced over the 4 k-quads
__device__ __forceinline__ float out_dot(half8v a0, half8v a1,
                                         const float* wfc0, const float* wfc1) {
    float s = 0.f;
#pragma unroll
    for (int j = 0; j < 8; ++j) s = fmaf((float)a0[j], wfc0[j], s);
#pragma unroll
    for (int j = 0; j < 8; ++j) s = fmaf((float)a1[j], wfc1[j], s);
    s += __shfl_xor(s, 16);
    s += __shfl_xor(s, 32);
    return s;   // full 64-dot for batch (lane&7), on all lanes
}

// 256 thr = 4 waves, 8 batches/block, 256 blocks. Wave w owns units 16w..16w+15.
// h lives in an 8-row LDS tile; the A-frag read replicates row m -> h[m&7], so
// D rows 8-15 duplicate batches 0-7 and quads 2/3 select elements 2/3 with one
// cndmask instead of cross-lane shfl (R5's 8 ds_permutes eliminated).
// Gate weights/biases are prescaled by -log2e (i,f,o) / 2log2e (g) so the
// MFMA output feeds ex2 directly.
__global__ __launch_bounds__(256, 1) void lstm_kernel(
    const float* __restrict__ x, const float* __restrict__ w_ih,
    const float* __restrict__ w_hh, const float* __restrict__ b_ih,
    const float* __restrict__ b_hh, const float* __restrict__ w_fc,
    const float* __restrict__ b_fc, float* __restrict__ out)
{
    __shared__ __align__(16) _Float16 hbuf[2][8 * HSTR];   // 2.25 KB
    __shared__ __align__(16) _Float16 xls[NB * XSTRIDE];   // 8.3 KB
    __shared__ __align__(16) float ols[NB * OSTRIDE];      // 16.4 KB

    const int tid  = threadIdx.x;
    const int w    = tid >> 6;        // wave 0..3
    const int lane = tid & 63;
    const int q    = lane >> 4;       // quad (A k-group / D row-group)
    const int c    = lane & 15;       // unit-in-tile / A-row
    const int hq   = q >> 1;          // 0: use acc elems {0,1}; 1: elems {2,3}
    const int xbase = 4 * (q & 1);    // x rows for this quad's D rows
    const int bat0  = xbase + 2 * hq; // first of this lane's 2 batches
    const int b0   = blockIdx.x * NB;

    // ---- stage x: global -> LDS (f16), coalesced float4 reads ----
    for (int i = tid; i < NB * 128; i += 256) {      // 8 rows x 128 float4
        int b  = i >> 7;
        int t4 = i & 127;
        float4 v = *(const float4*)(x + (size_t)(b0 + b) * T_STEPS + t4 * 4);
        half4v hv;
        hv[0] = (_Float16)v.x; hv[1] = (_Float16)v.y;
        hv[2] = (_Float16)v.z; hv[3] = (_Float16)v.w;
        *(half4v*)(&xls[b * XSTRIDE + t4 * 4]) = hv;
    }
    // zero both h buffers (h_{-1} = 0): 2*8*72 f16 = 576 dwords
    for (int i = tid; i < 2 * 8 * HSTR / 2; i += 256) ((int*)hbuf)[i] = 0;

    // ---- B fragments (prescaled weights) in VGPRs: tile n = gate class ----
    // lane (q,c) holds B[k=32kk+8q+jj][col c] = sK[n]*w_hh[g][k], g = 64n+16w+c
    const float sK[4] = { -K1, -K1, K2, -K1 };   // i,f sig; g tanh; o sig
    half8v bfrag[4][2];
    float biasS[4], wihS[4];
#pragma unroll
    for (int n = 0; n < 4; ++n) {
        int g = 64 * n + 16 * w + c;
        biasS[n] = (b_ih[g] + b_hh[g]) * sK[n];
        wihS[n]  = w_ih[g] * sK[n];
#pragma unroll
        for (int kk = 0; kk < 2; ++kk) {
            const float* wp = w_hh + g * 64 + 32 * kk + 8 * q;
            float4 lo  = *(const float4*)(wp);
            float4 hi4 = *(const float4*)(wp + 4);
            half8v f;
            f[0] = (_Float16)(lo.x  * sK[n]); f[1] = (_Float16)(lo.y  * sK[n]);
            f[2] = (_Float16)(lo.z  * sK[n]); f[3] = (_Float16)(lo.w  * sK[n]);
            f[4] = (_Float16)(hi4.x * sK[n]); f[5] = (_Float16)(hi4.y * sK[n]);
            f[6] = (_Float16)(hi4.z * sK[n]); f[7] = (_Float16)(hi4.w * sK[n]);
            bfrag[n][kk] = f;
        }
    }

    // fc weights aligned to this lane's A-frag k-slice
    float wfc0[8], wfc1[8];
#pragma unroll
    for (int j = 0; j < 8; ++j) { wfc0[j] = w_fc[8 * q + j]; wfc1[j] = w_fc[32 + 8 * q + j]; }
    const float bfc = b_fc[0];

    float cs[2] = {0.f, 0.f};   // cell state for (batch bat0+rr, unit 16w+c)

    __syncthreads();

    half8v sa0 = {}, sa1 = {};  // saved A-frags for rotated fc-dot

    for (int tq = 0; tq < 128; ++tq) {
        // x for this quad's 4 D-rows (batches xbase..xbase+3), 4 steps
        float xq[4][4];          // [r][dt]
#pragma unroll
        for (int r = 0; r < 4; ++r) {
            half4v hx = *(const half4v*)(&xls[(xbase + r) * XSTRIDE + tq * 4]);
            xq[r][0] = (float)hx[0]; xq[r][1] = (float)hx[1];
            xq[r][2] = (float)hx[2]; xq[r][3] = (float)hx[3];
        }

#pragma unroll
        for (int dt = 0; dt < 4; ++dt) {
            const int t  = tq * 4 + dt;
            const int rb = t & 1;
            const _Float16* hrd = hbuf[rb];

            // A-frags: A[m][k] = h[m&7][k]; lane row m=c -> LDS row c&7
            // (rows 8-15 broadcast-duplicate rows 0-7: free replication)
            const _Float16* hp = hrd + (c & 7) * HSTR + 8 * q;
            half8v a0 = *(const half8v*)(hp);        // k = 8q+j
            half8v a1 = *(const half8v*)(hp + 32);   // k = 32+8q+j

            if (dt == w) { sa0 = a0; sa1 = a1; }     // rotate fc-dot ownership

            // C-init = prescaled bias + x*wih for D rows 4q..4q+3
            f32x4 acc[4];
#pragma unroll
            for (int n = 0; n < 4; ++n) {
                f32x4 a;
                a[0] = fmaf(xq[0][dt], wihS[n], biasS[n]);
                a[1] = fmaf(xq[1][dt], wihS[n], biasS[n]);
                a[2] = fmaf(xq[2][dt], wihS[n], biasS[n]);
                a[3] = fmaf(xq[3][dt], wihS[n], biasS[n]);
                acc[n] = __builtin_amdgcn_mfma_f32_16x16x32_f16(a0, bfrag[n][0], a, 0, 0, 0);
                acc[n] = __builtin_amdgcn_mfma_f32_16x16x32_f16(a1, bfrag[n][1], acc[n], 0, 0, 0);
            }

            // element select: quads 0/1 use elems {0,1}; quads 2/3 use {2,3}
            // (1 cndmask each, wave-uniform cond -- replaces R5's shfl spread)
            float v[4][2];
#pragma unroll
            for (int n = 0; n < 4; ++n) {
                v[n][0] = hq ? acc[n][2] : acc[n][0];
                v[n][1] = hq ? acc[n][3] : acc[n][1];
            }

            // activations (args pre-scaled); lane owns (bat0+rr, unit 16w+c)
            _Float16* hwr = hbuf[rb ^ 1];
#pragma unroll
            for (int rr = 0; rr < 2; ++rr) {
                float A  = ex2(v[0][rr]);                 // e^{-i}
                float B  = ex2(v[2][rr]);                 // e^{2g}
                float ig = (B - 1.0f) * rcp_fast((1.0f + A) * (1.0f + B));
                float rf = rcp_fast(1.0f + ex2(v[1][rr])); // sig(f)
                cs[rr] = fmaf(cs[rr], rf, ig);
                float cc = fminf(fmaxf(cs[rr], -15.f), 15.f);
                float Ao = ex2(v[3][rr]);                 // e^{-o}
                float C  = ex2(cc * K2);                  // e^{2c}
                float h  = (C - 1.0f) * rcp_fast((1.0f + Ao) * (1.0f + C));
                hwr[(bat0 + rr) * HSTR + 16 * w + c] = (_Float16)h;
            }
            __syncthreads();
        }

        // rotated fc-dot: saved frag is A of step st = tq*4+w = h_{st-1};
        // after reduction lane holds batch (lane&7)'s dot
        {
            int st = tq * 4 + w;
            if (st > 0) {
                float s = out_dot(sa0, sa1, wfc0, wfc1);
                if (lane < NB) ols[lane * OSTRIDE + (st - 1)] = s + bfc;
            }
        }
    }

    // final output column: h_511 lives in hbuf[0]
    if (w == 3) {
        const _Float16* hp = hbuf[0] + (c & 7) * HSTR + 8 * q;
        half8v a0 = *(const half8v*)(hp);
        half8v a1 = *(const half8v*)(hp + 32);
        float s = out_dot(a0, a1, wfc0, wfc1);
        if (lane < NB) ols[lane * OSTRIDE + (T_STEPS - 1)] = s + bfc;
    }
    __syncthreads();

    // bulk store: LDS out -> global, coalesced
    for (int i = tid; i < NB * T_STEPS; i += 256) {
        int b = i >> 9;
        int t = i & (T_STEPS - 1);
        out[(size_t)(b0 + b) * T_STEPS + t] = ols[b * OSTRIDE + t];
    }
}

extern "C" void kernel_launch(void* const* d_in, const int* in_sizes, int n_in,
                              void* d_out, int out_size, void* d_ws, size_t ws_size,
                              hipStream_t stream) {
    const float* x    = (const float*)d_in[0];
    const float* w_ih = (const float*)d_in[1];
    const float* w_hh = (const float*)d_in[2];
    const float* b_ih = (const float*)d_in[3];
    const float* b_hh = (const float*)d_in[4];
    const float* w_fc = (const float*)d_in[5];
    const float* b_fc = (const float*)d_in[6];
    float* out = (float*)d_out;
    hipLaunchKernelGGL(lstm_kernel, dim3(2048 / NB), dim3(256), 0, stream,
                       x, w_ih, w_hh, b_ih, b_hh, w_fc, b_fc, out);
}